// Round 9
// baseline (1302.439 us; speedup 1.0000x reference)
//
#include <hip/hip_runtime.h>
#include <hip/hip_bf16.h>

#define B_SZ 8192
#define IH   2048
#define H_SZ 1024
#define BM   256
#define BK   64
#define NT   (IH / BK)      // 32 K-tiles (BK=64 variant)
#define NI   (NT / 2)
#define DBUF 65536
#define WOFF 32768

typedef __attribute__((ext_vector_type(8))) short  short8;
typedef __attribute__((ext_vector_type(4))) float  floatx4;

static __device__ __forceinline__ ushort f2bf(float f) {
  union { float f; unsigned u; } v; v.f = f;
  unsigned u = v.u;
  u += 0x7fffu + ((u >> 16) & 1u);
  return (ushort)(u >> 16);
}
static __device__ __forceinline__ float sigmoidf_(float x) {
  return 1.0f / (1.0f + __expf(-x));
}
static __device__ __forceinline__ float tanhf_(float x) {
  float ax = fabsf(x);
  float e = __expf(-2.0f * ax);
  float t = (1.0f - e) / (1.0f + e);
  return copysignf(t, x);
}
static __device__ __forceinline__ void gload_lds16(const void* gsrc, void* ldst) {
  __builtin_amdgcn_global_load_lds(
      (__attribute__((address_space(1))) const void*)gsrc,
      (__attribute__((address_space(3))) void*)ldst, 16, 0, 0);
}

// ---------------------------------------------------------------------------
// Pre-pass 1: W[k][n] fp32 -> Wt[g][n][k] bf16
// ---------------------------------------------------------------------------
__global__ __launch_bounds__(256) void convert_w_kernel(
    const float* __restrict__ Wf, const float* __restrict__ Wi,
    const float* __restrict__ Wo, const float* __restrict__ Wc,
    ushort* __restrict__ Wt) {
  __shared__ float tile[64][65];
  const int g  = blockIdx.z;
  const float* W = (g == 0) ? Wf : (g == 1) ? Wi : (g == 2) ? Wo : Wc;
  const int n0 = blockIdx.x * 64;
  const int k0 = blockIdx.y * 64;
  const int tid = threadIdx.x;
#pragma unroll
  for (int i = 0; i < 4; ++i) {
    int c = i * 256 + tid;
    int r = c >> 4, c4 = c & 15;
    float4 v = *(const float4*)(W + (size_t)(k0 + r) * H_SZ + n0 + c4 * 4);
    tile[r][c4 * 4 + 0] = v.x;
    tile[r][c4 * 4 + 1] = v.y;
    tile[r][c4 * 4 + 2] = v.z;
    tile[r][c4 * 4 + 3] = v.w;
  }
  __syncthreads();
  const int n  = tid >> 2;
  const int kc = (tid & 3) * 16;
  ushort o[16] __attribute__((aligned(16)));
#pragma unroll
  for (int e = 0; e < 16; ++e) o[e] = f2bf(tile[kc + e][n]);
  ushort* dst = Wt + ((size_t)g * H_SZ + n0 + n) * IH + k0 + kc;
  *(uint4*)(dst)     = *(uint4*)&o[0];
  *(uint4*)(dst + 8) = *(uint4*)&o[8];
}

// ---------------------------------------------------------------------------
// Pre-pass 2: A = [x | h_prev] fp32 -> Abf[8192][2048] bf16
// ---------------------------------------------------------------------------
__global__ __launch_bounds__(256) void convert_a_kernel(
    const float* __restrict__ x, const float* __restrict__ hp,
    ushort* __restrict__ Abf) {
  size_t idx = ((size_t)blockIdx.x * 256 + threadIdx.x) * 8;
  size_t row = idx >> 11;
  size_t col = idx & 2047;
  const float* src = (col < 1024) ? (x  + row * 1024 + col)
                                  : (hp + row * 1024 + (col - 1024));
  float4 v0 = *(const float4*)(src);
  float4 v1 = *(const float4*)(src + 4);
  ushort o[8] __attribute__((aligned(16)));
  o[0] = f2bf(v0.x); o[1] = f2bf(v0.y); o[2] = f2bf(v0.z); o[3] = f2bf(v0.w);
  o[4] = f2bf(v1.x); o[5] = f2bf(v1.y); o[6] = f2bf(v1.z); o[7] = f2bf(v1.w);
  *(uint4*)(Abf + idx) = *(uint4*)&o[0];
}

// ---------------------------------------------------------------------------
// Shared epilogue (acc[mf][2g+ns] layout, identical in both variants)
// ---------------------------------------------------------------------------
static __device__ __forceinline__ void lstm_epilogue(
    floatx4 (&acc)[4][8], const float* Cp,
    const float* bf_, const float* bi_, const float* bo_, const float* bc_,
    float* out, int b0, int n0g, int wm, int wn, int ln) {
  const int colq = ln & 15;
  const int rq   = ln >> 4;
  float* outh = out;
  float* outC = out + (size_t)B_SZ * H_SZ;
#pragma unroll
  for (int mf = 0; mf < 4; ++mf) {
#pragma unroll
    for (int ns = 0; ns < 2; ++ns) {
      int n = n0g + wn * 32 + ns * 16 + colq;
      float vbf = bf_[n], vbi = bi_[n], vbo = bo_[n], vbc = bc_[n];
#pragma unroll
      for (int r = 0; r < 4; ++r) {
        int row = b0 + wm * 64 + mf * 16 + rq * 4 + r;
        float fg = sigmoidf_(acc[mf][0 + ns][r] + vbf);
        float ig = sigmoidf_(acc[mf][2 + ns][r] + vbi);
        float og = sigmoidf_(acc[mf][4 + ns][r] + vbo);
        float cg = tanhf_  (acc[mf][6 + ns][r] + vbc);
        float cp = Cp[(size_t)row * H_SZ + n];
        float Ct = fg * cp + ig * cg;
        float ht = og * tanhf_(Ct);
        outh[(size_t)row * H_SZ + n] = ht;
        outC[(size_t)row * H_SZ + n] = Ct;
      }
    }
  }
}

// ---------------------------------------------------------------------------
// VARIANT B: BK=32, 64 KiB LDS -> 2 blocks/CU co-resident (cross-block
// overlap probe). 2 phases per K-tile, one vmcnt(0) drain per tile.
//
// LDS buf d (32 KiB at d*32768): A [256 rows][64 B] ; W at +16384 [256][64 B].
// Slot swizzle: 16B slot sl' = kg ^ ((row>>1)&3) (2-way max on frag reads,
// derived bank walk: quads 0-7 hit exactly 2x). Inverse applied on global
// source (rule 21): staging thread at LDS slot (row, sl) fetches k-group
// kg = sl ^ ((row>>1)&3).
//
// Per K-tile t (buf d=t&1, other e):  [tile t+1 -> buf e]
//  Ph_a: read aF0-3,bF0-3 (8); stage 4 gloads(t+1->e); BAR; 16 MFMA; BAR
//  Ph_b: read bF4-7 (4); BAR; 16 MFMA; vmcnt(0); BAR
// WAR: buf e last read in tile t-1, readers retired before its final BAR;
//   stage issued after. RAW: vmcnt(0) end-of-t drains t+1's 4 stages
//   (issued ~1.2k cyc earlier, >= 900-cyc HBM latency; residual covered by
//   the sibling block). Tail stage wraps (&63): dead data, never read.
// ---------------------------------------------------------------------------
__global__ __launch_bounds__(512, 4) void lstm_fused_bk32(
    const float* __restrict__ Cp, const ushort* __restrict__ Wt,
    const ushort* __restrict__ Abf,
    const float* __restrict__ bf_, const float* __restrict__ bi_,
    const float* __restrict__ bo_, const float* __restrict__ bc_,
    float* __restrict__ out) {
  __shared__ char lds2[2 * 32768];   // 64 KiB

  const int bid = blockIdx.x;
  const int wg  = (bid & 7) * 64 + (bid >> 3);
  const int b0  = (wg >> 4) * BM;
  const int n0g = (wg & 15) * 64;

  const int tid = threadIdx.x;
  const int ln  = tid & 63;
  const int wv  = tid >> 6;
  const int wm  = wv >> 1, wn = wv & 1;

  floatx4 acc[4][8];
#pragma unroll
  for (int m = 0; m < 4; ++m)
#pragma unroll
    for (int j = 0; j < 8; ++j) acc[m][j] = {0.f, 0.f, 0.f, 0.f};

  // read bases (x = slot swizzle, mf/gate deltas are immediates)
  const int x   = (ln >> 4) ^ (((ln & 15) >> 1) & 3);
  const int aB  = (wm * 64 + (ln & 15)) * 64 + x * 16;
  const int bB  = 16384 + (wn * 32 + (ln & 15)) * 64 + x * 16;

  // stage constants: slot s = i*512+tid: row = s>>2, sl = s&3
  const unsigned kgx = ((unsigned)(tid & 3)) ^ ((unsigned)(tid >> 3) & 3);
  const char* AbfB = (const char*)Abf;
  const char* WtB  = (const char*)Wt;
  unsigned aoff2[2], woff2[2];
#pragma unroll
  for (int i = 0; i < 2; ++i) {
    int row = i * 128 + (tid >> 2);
    aoff2[i] = (unsigned)(b0 + row) * 4096 + kgx * 16;
    int nrt = row;
    woff2[i] = (unsigned)((nrt >> 6) * 1024 + n0g + (nrt & 63)) * 4096 + kgx * 16;
  }
  const int dA0 = tid * 16, dA1 = 8192 + tid * 16;

#define SAB2(db, ktb)                                                         \
  do {                                                                        \
    gload_lds16(AbfB + (aoff2[0] + (unsigned)(ktb)), lds2 + (db) + dA0);      \
    gload_lds16(AbfB + (aoff2[1] + (unsigned)(ktb)), lds2 + (db) + dA1);      \
    gload_lds16(WtB  + (woff2[0] + (unsigned)(ktb)), lds2 + (db) + 16384 + dA0);\
    gload_lds16(WtB  + (woff2[1] + (unsigned)(ktb)), lds2 + (db) + 16384 + dA1);\
  } while (0)

  short8 aF2[4];
  short8 bF2[8];
#define RD_A2(d, mf)  (aF2[mf] = *(const short8*)(lds2 + (d) * 32768 + aB + (mf) * 1024))
#define RD_B2(d, j)   (bF2[j]  = *(const short8*)(lds2 + (d) * 32768 + bB +   \
                                   ((j) >> 1) * 4096 + ((j) & 1) * 1024))
#define MFQ2(jh)                                                              \
  do {                                                                        \
    __builtin_amdgcn_s_setprio(1);                                            \
    _Pragma("unroll")                                                         \
    for (int mf_ = 0; mf_ < 4; ++mf_)                                         \
      _Pragma("unroll")                                                       \
      for (int j_ = 4 * (jh); j_ < 4 * (jh) + 4; ++j_)                        \
        acc[mf_][j_] = __builtin_amdgcn_mfma_f32_16x16x32_bf16(               \
            aF2[mf_], bF2[j_], acc[mf_][j_], 0, 0, 0);                        \
    __builtin_amdgcn_s_setprio(0);                                            \
  } while (0)
#define BAR2   __builtin_amdgcn_s_barrier()
#define VMC0   asm volatile("s_waitcnt vmcnt(0)" ::: "memory")

  // prologue: tile 0 -> buf0
  SAB2(0, 0);
  VMC0; BAR2;

#pragma unroll 1
  for (int it = 0; it < 32; ++it) {
    const int ktbA = ((2 * it + 1) & 63) * 64;   // stage tile 2it+1 -> buf1
    const int ktbB = ((2 * it + 2) & 63) * 64;   // stage tile 2it+2 -> buf0
    // tile 2it (buf0)
    RD_A2(0, 0); RD_A2(0, 1); RD_A2(0, 2); RD_A2(0, 3);
    RD_B2(0, 0); RD_B2(0, 1); RD_B2(0, 2); RD_B2(0, 3);
    SAB2(32768, ktbA);
    BAR2; MFQ2(0); BAR2;
    RD_B2(0, 4); RD_B2(0, 5); RD_B2(0, 6); RD_B2(0, 7);
    BAR2; MFQ2(1); VMC0; BAR2;
    // tile 2it+1 (buf1)
    RD_A2(1, 0); RD_A2(1, 1); RD_A2(1, 2); RD_A2(1, 3);
    RD_B2(1, 0); RD_B2(1, 1); RD_B2(1, 2); RD_B2(1, 3);
    SAB2(0, ktbB);
    BAR2; MFQ2(0); BAR2;
    RD_B2(1, 4); RD_B2(1, 5); RD_B2(1, 6); RD_B2(1, 7);
    BAR2; MFQ2(1); VMC0; BAR2;
  }

  lstm_epilogue(acc, Cp, bf_, bi_, bo_, bc_, out, b0, n0g, wm, wn, ln);
#undef SAB2
#undef RD_A2
#undef RD_B2
#undef MFQ2
#undef BAR2
#undef VMC0
}

// ---------------------------------------------------------------------------
// VARIANT A (control): r8's 4-phase BK=64, 128 KiB LDS, 1 block/CU.
// ---------------------------------------------------------------------------
__global__ __launch_bounds__(512, 2) void lstm_fused_kernel(
    const float* __restrict__ Cp, const ushort* __restrict__ Wt,
    const ushort* __restrict__ Abf,
    const float* __restrict__ bf_, const float* __restrict__ bi_,
    const float* __restrict__ bo_, const float* __restrict__ bc_,
    float* __restrict__ out) {
  __shared__ char lds[2 * DBUF];

  const int bid = blockIdx.x;
  const int wg  = (bid & 7) * 64 + (bid >> 3);
  const int b0  = (wg >> 4) * BM;
  const int n0g = (wg & 15) * 64;

  const int tid = threadIdx.x;
  const int ln  = tid & 63;
  const int wv  = tid >> 6;
  const int wm  = wv >> 1, wn = wv & 1;

  floatx4 acc[4][8];
#pragma unroll
  for (int m = 0; m < 4; ++m)
#pragma unroll
    for (int j = 0; j < 8; ++j) acc[m][j] = {0.f, 0.f, 0.f, 0.f};

  const int sw  = (ln & 7) << 4;
  const int kb0 = (((ln >> 4) << 4)) ^ sw;
  const int kb1 = (64 + ((ln >> 4) << 4)) ^ sw;
  const int aR  = (wm * 64 + (ln & 15)) * 128;
  const int bR  = WOFF + (wn * 32 + (ln & 15)) * 128;
  int aB0[2], aB1[2], bB0[2], bB1[2];
#pragma unroll
  for (int d = 0; d < 2; ++d) {
    aB0[d] = d * DBUF + aR + kb0;  aB1[d] = d * DBUF + aR + kb1;
    bB0[d] = d * DBUF + bR + kb0;  bB1[d] = d * DBUF + bR + kb1;
  }

  const unsigned kcsw = ((tid & 7) * 16) ^ (((tid >> 3) & 7) << 4);
  const char*  AbfB = (const char*)Abf;
  const char*  WtB  = (const char*)Wt;
  unsigned aoff[2];
#pragma unroll
  for (int i = 0; i < 2; ++i)
    aoff[i] = ((unsigned)(b0 + i * 64 + (tid >> 3)) << 12) + kcsw;
  unsigned woff[2][2];
#pragma unroll
  for (int h = 0; h < 2; ++h)
#pragma unroll
    for (int i = 0; i < 2; ++i) {
      int nrt  = h * 128 + i * 64 + (tid >> 3);
      int g    = nrt >> 6, nloc = nrt & 63;
      woff[h][i] = ((unsigned)(g * H_SZ + n0g + nloc) << 12) + kcsw;
    }
  int dsto[2];
#pragma unroll
  for (int i = 0; i < 2; ++i) dsto[i] = (i * 512 + wv * 64) * 16;

#define STAGE_A(db, ktb, h)                                                   \
  do {                                                                        \
    gload_lds16(AbfB + (aoff[0] + ((unsigned)(h) << 19) + (unsigned)(ktb)),   \
                lds + (db) + (h) * 16384 + dsto[0]);                          \
    gload_lds16(AbfB + (aoff[1] + ((unsigned)(h) << 19) + (unsigned)(ktb)),   \
                lds + (db) + (h) * 16384 + dsto[1]);                          \
  } while (0)
#define STAGE_W(db, ktb, h)                                                   \
  do {                                                                        \
    gload_lds16(WtB + (woff[h][0] + (unsigned)(ktb)),                         \
                lds + (db) + WOFF + (h) * 16384 + dsto[0]);                   \
    gload_lds16(WtB + (woff[h][1] + (unsigned)(ktb)),                         \
                lds + (db) + WOFF + (h) * 16384 + dsto[1]);                   \
  } while (0)

  short8 aF[4][2];
  short8 bF[8][2];
#define RD_A(dbi, mf)                                                         \
  do {                                                                        \
    aF[mf][0] = *(const short8*)(lds + aB0[dbi] + (mf) * 2048);               \
    aF[mf][1] = *(const short8*)(lds + aB1[dbi] + (mf) * 2048);               \
  } while (0)
#define RD_B(dbi, j)                                                          \
  do {                                                                        \
    bF[j][0] = *(const short8*)(lds + bB0[dbi] + ((j) >> 1) * 8192 +          \
                                ((j) & 1) * 2048);                            \
    bF[j][1] = *(const short8*)(lds + bB1[dbi] + ((j) >> 1) * 8192 +          \
                                ((j) & 1) * 2048);                            \
  } while (0)
#define RDQA(d)  do { RD_A(d, 0); RD_A(d, 1); RD_A(d, 2); RD_A(d, 3); } while (0)
#define RDB03(d) do { RD_B(d, 0); RD_B(d, 1); RD_B(d, 2); RD_B(d, 3); } while (0)
#define RDB47(d) do { RD_B(d, 4); RD_B(d, 5); RD_B(d, 6); RD_B(d, 7); } while (0)
#define MFQ(jh)                                                               \
  do {                                                                        \
    __builtin_amdgcn_s_setprio(1);                                            \
    _Pragma("unroll")                                                         \
    for (int k_ = 0; k_ < 2; ++k_)                                            \
      _Pragma("unroll")                                                       \
      for (int mf_ = 0; mf_ < 4; ++mf_)                                       \
        _Pragma("unroll")                                                     \
        for (int j_ = 4 * (jh); j_ < 4 * (jh) + 4; ++j_)                      \
          acc[mf_][j_] = __builtin_amdgcn_mfma_f32_16x16x32_bf16(             \
              aF[mf_][k_], bF[j_][k_], acc[mf_][j_], 0, 0, 0);                \
    __builtin_amdgcn_s_setprio(0);                                            \
  } while (0)
#define BAR   __builtin_amdgcn_s_barrier()
#define VMC(n) asm volatile("s_waitcnt vmcnt(" #n ")" ::: "memory")

  STAGE_W(0, 0, 0); STAGE_A(0, 0, 0); STAGE_A(0, 0, 1); STAGE_W(0, 0, 1);
  STAGE_W(DBUF, 128, 0); STAGE_A(DBUF, 128, 0); STAGE_A(DBUF, 128, 1);
  VMC(6);
  BAR;

#pragma unroll 1
  for (int it = 0; it < NI; ++it) {
    const int kt1b  = (2 * it + 1) * 128;
    const int ktn0b = ((2 * it + 2) & 31) * 128;
    const int ktn1b = ((2 * it + 3) & 31) * 128;
    RDQA(0); RDB03(0);
    STAGE_W(DBUF, kt1b, 1);
    BAR; MFQ(0); BAR;
    RDB47(0);
    STAGE_W(0, ktn0b, 0); STAGE_A(0, ktn0b, 0);
    BAR; MFQ(1); VMC(4); BAR;
    RDQA(1); RDB03(1);
    STAGE_A(0, ktn0b, 1); STAGE_W(0, ktn0b, 1);
    BAR; MFQ(0); BAR;
    RDB47(1);
    STAGE_W(DBUF, ktn1b, 0); STAGE_A(DBUF, ktn1b, 0); STAGE_A(DBUF, ktn1b, 1);
    BAR; MFQ(1); VMC(6); BAR;
  }

  lstm_epilogue(acc, Cp, bf_, bi_, bo_, bc_, out, b0, n0g, wm, wn, ln);
#undef STAGE_A
#undef STAGE_W
#undef RD_A
#undef RD_B
#undef RDQA
#undef RDB03
#undef RDB47
#undef MFQ
#undef BAR
#undef VMC
}

extern "C" void kernel_launch(void* const* d_in, const int* in_sizes, int n_in,
                              void* d_out, int out_size, void* d_ws, size_t ws_size,
                              hipStream_t stream) {
  const float* x  = (const float*)d_in[0];
  const float* hp = (const float*)d_in[1];
  const float* Cp = (const float*)d_in[2];
  const float* Wf = (const float*)d_in[3];
  const float* bf = (const float*)d_in[4];
  const float* Wi = (const float*)d_in[5];
  const float* bi = (const float*)d_in[6];
  const float* Wc = (const float*)d_in[7];
  const float* bc = (const float*)d_in[8];
  const float* Wo = (const float*)d_in[9];
  const float* bo = (const float*)d_in[10];

  ushort* Wt  = (ushort*)d_ws;                           // 16 MiB
  ushort* Abf = (ushort*)((char*)d_ws + (16u << 20));    // 32 MiB

  dim3 gridT(16, 32, 4);
  convert_w_kernel<<<gridT, 256, 0, stream>>>(Wf, Wi, Wo, Wc, Wt);
  convert_a_kernel<<<8192, 256, 0, stream>>>(x, hp, Abf);

  // A/B probe: variant B (BK=32, 2 blocks/CU) first, control A second.
  // Both compute the full identical output; final d_out = A's (known-good).
  lstm_fused_bk32<<<512, 512, 0, stream>>>(Cp, Wt, Abf,
                                           bf, bi, bo, bc, (float*)d_out);
  lstm_fused_kernel<<<512, 512, 0, stream>>>(Cp, Wt, Abf,
                                             bf, bi, bo, bc, (float*)d_out);
}

// Round 10
// 221.119 us; speedup vs baseline: 5.8902x; 5.8902x over previous
//
#include <hip/hip_runtime.h>
#include <hip/hip_bf16.h>

#define B_SZ 8192
#define IH   2048
#define H_SZ 1024
#define BM   256            // rows per block
#define BK   64             // K per tile
#define NT   (IH / BK)      // 32 K-tiles
#define WBUF 32768          // one W buffer: [256 nrt][128 B]

typedef __attribute__((ext_vector_type(8))) short  short8;
typedef __attribute__((ext_vector_type(4))) float  floatx4;

static __device__ __forceinline__ ushort f2bf(float f) {
  union { float f; unsigned u; } v; v.f = f;
  unsigned u = v.u;
  u += 0x7fffu + ((u >> 16) & 1u);   // RNE
  return (ushort)(u >> 16);
}
static __device__ __forceinline__ float sigmoidf_(float x) {
  return 1.0f / (1.0f + __expf(-x));
}
static __device__ __forceinline__ float tanhf_(float x) {
  float ax = fabsf(x);
  float e = __expf(-2.0f * ax);
  float t = (1.0f - e) / (1.0f + e);
  return copysignf(t, x);
}
static __device__ __forceinline__ void gload_lds16(const void* gsrc, void* ldst) {
  __builtin_amdgcn_global_load_lds(
      (__attribute__((address_space(1))) const void*)gsrc,
      (__attribute__((address_space(3))) void*)ldst, 16, 0, 0);
}

// ---------------------------------------------------------------------------
// Pre-pass 1: W[k][n] fp32 -> Wt[g][n][k] bf16 (K-contiguous for MFMA B-frag)
// ---------------------------------------------------------------------------
__global__ __launch_bounds__(256) void convert_w_kernel(
    const float* __restrict__ Wf, const float* __restrict__ Wi,
    const float* __restrict__ Wo, const float* __restrict__ Wc,
    ushort* __restrict__ Wt) {
  __shared__ float tile[64][65];
  const int g  = blockIdx.z;
  const float* W = (g == 0) ? Wf : (g == 1) ? Wi : (g == 2) ? Wo : Wc;
  const int n0 = blockIdx.x * 64;
  const int k0 = blockIdx.y * 64;
  const int tid = threadIdx.x;
#pragma unroll
  for (int i = 0; i < 4; ++i) {
    int c = i * 256 + tid;
    int r = c >> 4, c4 = c & 15;
    float4 v = *(const float4*)(W + (size_t)(k0 + r) * H_SZ + n0 + c4 * 4);
    tile[r][c4 * 4 + 0] = v.x;
    tile[r][c4 * 4 + 1] = v.y;
    tile[r][c4 * 4 + 2] = v.z;
    tile[r][c4 * 4 + 3] = v.w;
  }
  __syncthreads();
  const int n  = tid >> 2;
  const int kc = (tid & 3) * 16;
  ushort o[16] __attribute__((aligned(16)));
#pragma unroll
  for (int e = 0; e < 16; ++e) o[e] = f2bf(tile[kc + e][n]);
  ushort* dst = Wt + ((size_t)g * H_SZ + n0 + n) * IH + k0 + kc;
  *(uint4*)(dst)     = *(uint4*)&o[0];
  *(uint4*)(dst + 8) = *(uint4*)&o[8];
}

// ---------------------------------------------------------------------------
// Pre-pass 2: A = [x | h_prev] fp32 -> Abf[8192][2048] bf16
// ---------------------------------------------------------------------------
__global__ __launch_bounds__(256) void convert_a_kernel(
    const float* __restrict__ x, const float* __restrict__ hp,
    ushort* __restrict__ Abf) {
  size_t idx = ((size_t)blockIdx.x * 256 + threadIdx.x) * 8;
  size_t row = idx >> 11;
  size_t col = idx & 2047;
  const float* src = (col < 1024) ? (x  + row * 1024 + col)
                                  : (hp + row * 1024 + (col - 1024));
  float4 v0 = *(const float4*)(src);
  float4 v1 = *(const float4*)(src + 4);
  ushort o[8] __attribute__((aligned(16)));
  o[0] = f2bf(v0.x); o[1] = f2bf(v0.y); o[2] = f2bf(v0.z); o[3] = f2bf(v0.w);
  o[4] = f2bf(v1.x); o[5] = f2bf(v1.y); o[6] = f2bf(v1.z); o[7] = f2bf(v1.w);
  *(uint4*)(Abf + idx) = *(uint4*)&o[0];
}

// ---------------------------------------------------------------------------
// Fused 4-gate GEMM + LSTM epilogue — A-DIRECT structure:
//   * A fragments load straight from global Abf into ping-pong registers
//     (16 B contiguous, fully-coalesced 64 B lines; L2/L1 pipe — parallel to
//     LDS). Prefetched one FULL K-tile ahead (~2400 cyc to hide latency).
//   * LDS holds only W: 2 x 32 KiB double buffer [256 nrt][128 B], row
//     swizzle byte^=(row&7)<<4 via pre-swizzled global source (rule 21).
//   * ONE barrier per K-tile. vmcnt(0) drain amortized over a whole tile.
//
// Per K-tile t (W in buf[t&1]):
//   issue 8 global_load_dwordx4 -> aN (A for t+1)
//   issue 4 gload_lds -> buf[(t+1)&1] (W for t+1)
//   ds_read bF j0-3 (8 b128); 32 MFMA (aC x bF03)
//   ds_read bF j4-7 (8 b128); 32 MFMA
//   vmcnt(0); s_barrier; swap aC/aN (static names, rule 20)
// Ledger: W(t+1) overwrites buf[(t+1)&1] = W(t-1), whose readers passed the
//   end-of-(t-1) barrier before this stage issues (1 barrier in between). ✓
//   W(t+1)/A(t+1) landed by end-of-t's vmcnt(0)+barrier => visible at t+1. ✓
//   A is wave-private (registers): no cross-wave hazard. ✓
//   Tail (t=31) prefetches kt&31=0: dead data, constant time. ✓
// ---------------------------------------------------------------------------
__global__ __launch_bounds__(512, 2) void lstm_fused_kernel(
    const float* __restrict__ Cp, const ushort* __restrict__ Wt,
    const ushort* __restrict__ Abf,
    const float* __restrict__ bf_, const float* __restrict__ bi_,
    const float* __restrict__ bo_, const float* __restrict__ bc_,
    float* __restrict__ out) {
  __shared__ char lds[2 * WBUF];   // 64 KiB

  const int bid = blockIdx.x;
  const int wg  = (bid & 7) * 64 + (bid >> 3);   // bijective, 512 % 8 == 0
  const int b0  = (wg >> 4) * BM;                // 32 M-tiles
  const int n0g = (wg & 15) * 64;                // 16 N-tiles (64 cols/gate)

  const int tid = threadIdx.x;
  const int ln  = tid & 63;
  const int wv  = tid >> 6;
  const int wm  = wv >> 1, wn = wv & 1;

  floatx4 acc[4][8];
#pragma unroll
  for (int m = 0; m < 4; ++m)
#pragma unroll
    for (int j = 0; j < 8; ++j) acc[m][j] = {0.f, 0.f, 0.f, 0.f};

  // ---- pinned W ds_read bases (W at LDS offset 0 now) ----
  const int sw  = (ln & 7) << 4;
  const int kb0 = (((ln >> 4) << 4)) ^ sw;
  const int kb1 = (64 + ((ln >> 4) << 4)) ^ sw;
  const int bR  = (wn * 32 + (ln & 15)) * 128;
  int bB0[2], bB1[2];
#pragma unroll
  for (int d = 0; d < 2; ++d) {
    bB0[d] = d * WBUF + bR + kb0;
    bB1[d] = d * WBUF + bR + kb1;
  }

  // ---- A direct-load base addresses (row-contiguous 16 B frags) ----
  const char* aA[4];
#pragma unroll
  for (int mf = 0; mf < 4; ++mf)
    aA[mf] = (const char*)Abf +
             ((size_t)(b0 + wm * 64 + mf * 16 + (ln & 15)) << 12) +
             ((ln >> 4) << 4);

  // ---- W stage constants ----
  const unsigned kcsw = ((tid & 7) * 16) ^ (((tid >> 3) & 7) << 4);
  const char* WtB = (const char*)Wt;
  unsigned woff[2][2];
#pragma unroll
  for (int h = 0; h < 2; ++h)
#pragma unroll
    for (int i = 0; i < 2; ++i) {
      int nrt  = h * 128 + i * 64 + (tid >> 3);
      int g    = nrt >> 6, nloc = nrt & 63;
      woff[h][i] = ((unsigned)(g * H_SZ + n0g + nloc) << 12) + kcsw;
    }
  int dsto[2];
#pragma unroll
  for (int i = 0; i < 2; ++i) dsto[i] = (i * 512 + wv * 64) * 16;

#define STAGE_W(db, ktb, h)                                                   \
  do {                                                                        \
    gload_lds16(WtB + (woff[h][0] + (unsigned)(ktb)),                         \
                lds + (db) + (h) * 16384 + dsto[0]);                          \
    gload_lds16(WtB + (woff[h][1] + (unsigned)(ktb)),                         \
                lds + (db) + (h) * 16384 + dsto[1]);                          \
  } while (0)

  short8 aCe[4][2], aCo[4][2];
  short8 bF[8][2];
#define RD_B(dbi, j)                                                          \
  do {                                                                        \
    bF[j][0] = *(const short8*)(lds + bB0[dbi] + ((j) >> 1) * 8192 +          \
                                ((j) & 1) * 2048);                            \
    bF[j][1] = *(const short8*)(lds + bB1[dbi] + ((j) >> 1) * 8192 +          \
                                ((j) & 1) * 2048);                            \
  } while (0)
#define RDB03(d) do { RD_B(d, 0); RD_B(d, 1); RD_B(d, 2); RD_B(d, 3); } while (0)
#define RDB47(d) do { RD_B(d, 4); RD_B(d, 5); RD_B(d, 6); RD_B(d, 7); } while (0)
// 32 MFMA: k outer, mf mid, j inner -> no back-to-back same-acc.
#define MFQ(AC, jh)                                                           \
  do {                                                                        \
    __builtin_amdgcn_s_setprio(1);                                            \
    _Pragma("unroll")                                                         \
    for (int k_ = 0; k_ < 2; ++k_)                                            \
      _Pragma("unroll")                                                       \
      for (int mf_ = 0; mf_ < 4; ++mf_)                                       \
        _Pragma("unroll")                                                     \
        for (int j_ = 4 * (jh); j_ < 4 * (jh) + 4; ++j_)                      \
          acc[mf_][j_] = __builtin_amdgcn_mfma_f32_16x16x32_bf16(             \
              AC[mf_][k_], bF[j_][k_], acc[mf_][j_], 0, 0, 0);                \
    __builtin_amdgcn_s_setprio(0);                                            \
  } while (0)
#define BAR   __builtin_amdgcn_s_barrier()
#define VMC(n) asm volatile("s_waitcnt vmcnt(" #n ")" ::: "memory")

#define LOADA(AN, ktnb_)                                                      \
  do {                                                                        \
    _Pragma("unroll")                                                         \
    for (int mf_ = 0; mf_ < 4; ++mf_) {                                       \
      AN[mf_][0] = *(const short8*)(aA[mf_] + (ktnb_));                       \
      AN[mf_][1] = *(const short8*)(aA[mf_] + (ktnb_) + 64);                  \
    }                                                                         \
  } while (0)

// One K-tile: consume AC + buf[BUFI]; prefetch A/W for tile KTN into AN /
// buf[KTN&1]. Single vmcnt(0)+barrier at the end.
#define TILE(BUFI, AC, AN, KTN)                                               \
  do {                                                                        \
    const int ktnb_ = ((KTN) & 31) * 128;                                     \
    LOADA(AN, ktnb_);                                                         \
    STAGE_W(((KTN) & 1) * WBUF, ktnb_, 0);                                    \
    STAGE_W(((KTN) & 1) * WBUF, ktnb_, 1);                                    \
    RDB03(BUFI); MFQ(AC, 0);                                                  \
    RDB47(BUFI); MFQ(AC, 1);                                                  \
    VMC(0); BAR;                                                              \
  } while (0)

  // ---- prologue: W(0) -> buf0 (4 gloads), A(0) -> aCe (8 loads) ----
  STAGE_W(0, 0, 0); STAGE_W(0, 0, 1);
  LOADA(aCe, 0);
  VMC(8);      // retire W(0); A(0) waited by compiler before first MFMA use
  BAR;

#pragma unroll 1
  for (int it = 0; it < NT / 2; ++it) {
    TILE(0, aCe, aCo, 2 * it + 1);   // tile 2it   (W in buf0)
    TILE(1, aCo, aCe, 2 * it + 2);   // tile 2it+1 (W in buf1)
  }

  // ---- epilogue: gate g at acc[mf][2g+ns]; same lane/reg across gates ----
  const int colq = ln & 15;
  const int rq   = ln >> 4;
  float* outh = out;
  float* outC = out + (size_t)B_SZ * H_SZ;
#pragma unroll
  for (int mf = 0; mf < 4; ++mf) {
#pragma unroll
    for (int ns = 0; ns < 2; ++ns) {
      int n = n0g + wn * 32 + ns * 16 + colq;
      float vbf = bf_[n], vbi = bi_[n], vbo = bo_[n], vbc = bc_[n];
#pragma unroll
      for (int r = 0; r < 4; ++r) {
        int row = b0 + wm * 64 + mf * 16 + rq * 4 + r;
        float fg = sigmoidf_(acc[mf][0 + ns][r] + vbf);
        float ig = sigmoidf_(acc[mf][2 + ns][r] + vbi);
        float og = sigmoidf_(acc[mf][4 + ns][r] + vbo);
        float cg = tanhf_  (acc[mf][6 + ns][r] + vbc);
        float cp = Cp[(size_t)row * H_SZ + n];
        float Ct = fg * cp + ig * cg;
        float ht = og * tanhf_(Ct);
        outh[(size_t)row * H_SZ + n] = ht;
        outC[(size_t)row * H_SZ + n] = Ct;
      }
    }
  }
#undef STAGE_W
#undef RD_B
#undef RDB03
#undef RDB47
#undef MFQ
#undef BAR
#undef VMC
#undef LOADA
#undef TILE
}

extern "C" void kernel_launch(void* const* d_in, const int* in_sizes, int n_in,
                              void* d_out, int out_size, void* d_ws, size_t ws_size,
                              hipStream_t stream) {
  const float* x  = (const float*)d_in[0];
  const float* hp = (const float*)d_in[1];
  const float* Cp = (const float*)d_in[2];
  const float* Wf = (const float*)d_in[3];
  const float* bf = (const float*)d_in[4];
  const float* Wi = (const float*)d_in[5];
  const float* bi = (const float*)d_in[6];
  const float* Wc = (const float*)d_in[7];
  const float* bc = (const float*)d_in[8];
  const float* Wo = (const float*)d_in[9];
  const float* bo = (const float*)d_in[10];

  ushort* Wt  = (ushort*)d_ws;                           // 16 MiB
  ushort* Abf = (ushort*)((char*)d_ws + (16u << 20));    // 32 MiB

  dim3 gridT(16, 32, 4);
  convert_w_kernel<<<gridT, 256, 0, stream>>>(Wf, Wi, Wo, Wc, Wt);
  convert_a_kernel<<<8192, 256, 0, stream>>>(x, hp, Abf);

  lstm_fused_kernel<<<512, 512, 0, stream>>>(Cp, Wt, Abf,
                                             bf, bi, bo, bc, (float*)d_out);
}

// Round 11
// 156.770 us; speedup vs baseline: 8.3080x; 1.4105x over previous
//
#include <hip/hip_runtime.h>
#include <hip/hip_bf16.h>

#define B_SZ 8192
#define IH   2048
#define H_SZ 1024
#define BM   256            // rows per block
#define BK   64             // K per tile
#define NT   (IH / BK)      // 32 K-tiles
#define NI   (NT / 2)       // 16 iterations, 2 K-tiles each
#define DBUF 65536          // one dbuf: A [256][128B] + W [256][128B]
#define WOFF 32768          // W region offset inside a dbuf

typedef __attribute__((ext_vector_type(8))) short  short8;
typedef __attribute__((ext_vector_type(4))) float  floatx4;

static __device__ __forceinline__ ushort f2bf(float f) {
  union { float f; unsigned u; } v; v.f = f;
  unsigned u = v.u;
  u += 0x7fffu + ((u >> 16) & 1u);   // RNE
  return (ushort)(u >> 16);
}
static __device__ __forceinline__ float sigmoidf_(float x) {
  return 1.0f / (1.0f + __expf(-x));
}
static __device__ __forceinline__ float tanhf_(float x) {
  float ax = fabsf(x);
  float e = __expf(-2.0f * ax);
  float t = (1.0f - e) / (1.0f + e);
  return copysignf(t, x);
}
static __device__ __forceinline__ void gload_lds16(const void* gsrc, void* ldst) {
  __builtin_amdgcn_global_load_lds(
      (__attribute__((address_space(1))) const void*)gsrc,
      (__attribute__((address_space(3))) void*)ldst, 16, 0, 0);
}

// ---------------------------------------------------------------------------
// Pre-pass 1: W[k][n] fp32 -> Wt[g][n][k] bf16 (K-contiguous for MFMA B-frag)
// ---------------------------------------------------------------------------
__global__ __launch_bounds__(256) void convert_w_kernel(
    const float* __restrict__ Wf, const float* __restrict__ Wi,
    const float* __restrict__ Wo, const float* __restrict__ Wc,
    ushort* __restrict__ Wt) {
  __shared__ float tile[64][65];
  const int g  = blockIdx.z;
  const float* W = (g == 0) ? Wf : (g == 1) ? Wi : (g == 2) ? Wo : Wc;
  const int n0 = blockIdx.x * 64;
  const int k0 = blockIdx.y * 64;
  const int tid = threadIdx.x;
#pragma unroll
  for (int i = 0; i < 4; ++i) {
    int c = i * 256 + tid;
    int r = c >> 4, c4 = c & 15;
    float4 v = *(const float4*)(W + (size_t)(k0 + r) * H_SZ + n0 + c4 * 4);
    tile[r][c4 * 4 + 0] = v.x;
    tile[r][c4 * 4 + 1] = v.y;
    tile[r][c4 * 4 + 2] = v.z;
    tile[r][c4 * 4 + 3] = v.w;
  }
  __syncthreads();
  const int n  = tid >> 2;
  const int kc = (tid & 3) * 16;
  ushort o[16] __attribute__((aligned(16)));
#pragma unroll
  for (int e = 0; e < 16; ++e) o[e] = f2bf(tile[kc + e][n]);
  ushort* dst = Wt + ((size_t)g * H_SZ + n0 + n) * IH + k0 + kc;
  *(uint4*)(dst)     = *(uint4*)&o[0];
  *(uint4*)(dst + 8) = *(uint4*)&o[8];
}

// ---------------------------------------------------------------------------
// Pre-pass 2: A = [x | h_prev] fp32 -> Abf[8192][2048] bf16
// ---------------------------------------------------------------------------
__global__ __launch_bounds__(256) void convert_a_kernel(
    const float* __restrict__ x, const float* __restrict__ hp,
    ushort* __restrict__ Abf) {
  size_t idx = ((size_t)blockIdx.x * 256 + threadIdx.x) * 8;
  size_t row = idx >> 11;
  size_t col = idx & 2047;
  const float* src = (col < 1024) ? (x  + row * 1024 + col)
                                  : (hp + row * 1024 + (col - 1024));
  float4 v0 = *(const float4*)(src);
  float4 v1 = *(const float4*)(src + 4);
  ushort o[8] __attribute__((aligned(16)));
  o[0] = f2bf(v0.x); o[1] = f2bf(v0.y); o[2] = f2bf(v0.z); o[3] = f2bf(v0.w);
  o[4] = f2bf(v1.x); o[5] = f2bf(v1.y); o[6] = f2bf(v1.z); o[7] = f2bf(v1.w);
  *(uint4*)(Abf + idx) = *(uint4*)&o[0];
}

// ---------------------------------------------------------------------------
// Fused 4-gate GEMM + LSTM epilogue — r4's verified 8-phase skeleton with
// m201's WAVE-TILE ORIENTATION: 8 waves = 2M x 4N; per-wave output
// 128 rows x (4 gates x 16 cols). Each wave reads ONE A-half (aF 8 frags,
// 16 b128/K-tile) + a quarter-slice of W (bF 4 frags = 4 gates, 8 b128).
// Read mix per phase: 12/8/4/0 (m201's); MFQ quadrant = 4mf x 2j x 2k = 16.
// Gate-locality preserved: acc[mf][g], all four gates in the same lane/reg.
//
// Everything else byte-identical to the r4 verified ledger:
// stage slots P1{d1.W1} P2{d0.W0} P3{d0.A0} P4{d0.A1} P5{d0.W1} P6{d1.W0}
// P7{d1.A0} P8{d1.A1}; VMC(6) at P4/P8; LGKM0 before each MFQ; row-swizzle
// byte^=(row&7)<<4 via pre-swizzled global source (rule 21).
// ---------------------------------------------------------------------------
__global__ __launch_bounds__(512, 2) void lstm_fused_kernel(
    const float* __restrict__ Cp, const ushort* __restrict__ Wt,
    const ushort* __restrict__ Abf,
    const float* __restrict__ bf_, const float* __restrict__ bi_,
    const float* __restrict__ bo_, const float* __restrict__ bc_,
    float* __restrict__ out) {
  __shared__ char lds[2 * DBUF];   // 128 KiB

  const int bid = blockIdx.x;
  const int wg  = (bid & 7) * 64 + (bid >> 3);   // bijective, 512 % 8 == 0
  const int b0  = (wg >> 4) * BM;                // 32 M-tiles
  const int n0g = (wg & 15) * 64;                // 16 N-tiles (64 cols/gate)

  const int tid = threadIdx.x;
  const int ln  = tid & 63;
  const int wv  = tid >> 6;
  const int wm  = wv >> 2;        // 2 M-groups (128 rows each)
  const int wn  = wv & 3;         // 4 N-groups (16 cols/gate each)

  floatx4 acc[8][4];              // [mf][gate]
#pragma unroll
  for (int m = 0; m < 8; ++m)
#pragma unroll
    for (int j = 0; j < 4; ++j) acc[m][j] = {0.f, 0.f, 0.f, 0.f};

  // ---- pinned ds_read bases ----
  const int sw  = (ln & 7) << 4;
  const int kb0 = (((ln >> 4) << 4)) ^ sw;
  const int kb1 = (64 + ((ln >> 4) << 4)) ^ sw;
  const int aR  = (wm * 128 + (ln & 15)) * 128;        // A-half per wm
  const int bR  = WOFF + (wn * 16 + (ln & 15)) * 128;  // gate stride = imm
  int aB0[2], aB1[2], bB0[2], bB1[2];
#pragma unroll
  for (int d = 0; d < 2; ++d) {
    aB0[d] = d * DBUF + aR + kb0;  aB1[d] = d * DBUF + aR + kb1;
    bB0[d] = d * DBUF + bR + kb0;  bB1[d] = d * DBUF + bR + kb1;
  }

  // ---- stage constants (32-bit offsets) ----
  const unsigned kcsw = ((tid & 7) * 16) ^ (((tid >> 3) & 7) << 4);
  const char*  AbfB = (const char*)Abf;
  const char*  WtB  = (const char*)Wt;
  unsigned aoff[2];
#pragma unroll
  for (int i = 0; i < 2; ++i)
    aoff[i] = ((unsigned)(b0 + i * 64 + (tid >> 3)) << 12) + kcsw;
  unsigned woff[2][2];
#pragma unroll
  for (int h = 0; h < 2; ++h)
#pragma unroll
    for (int i = 0; i < 2; ++i) {
      int nrt  = h * 128 + i * 64 + (tid >> 3);
      int g    = nrt >> 6, nloc = nrt & 63;
      woff[h][i] = ((unsigned)(g * H_SZ + n0g + nloc) << 12) + kcsw;
    }
  int dsto[2];
#pragma unroll
  for (int i = 0; i < 2; ++i) dsto[i] = (i * 512 + wv * 64) * 16;

#define STAGE_A(db, ktb, h)                                                   \
  do {                                                                        \
    gload_lds16(AbfB + (aoff[0] + ((unsigned)(h) << 19) + (unsigned)(ktb)),   \
                lds + (db) + (h) * 16384 + dsto[0]);                          \
    gload_lds16(AbfB + (aoff[1] + ((unsigned)(h) << 19) + (unsigned)(ktb)),   \
                lds + (db) + (h) * 16384 + dsto[1]);                          \
  } while (0)
#define STAGE_W(db, ktb, h)                                                   \
  do {                                                                        \
    gload_lds16(WtB + (woff[h][0] + (unsigned)(ktb)),                         \
                lds + (db) + WOFF + (h) * 16384 + dsto[0]);                   \
    gload_lds16(WtB + (woff[h][1] + (unsigned)(ktb)),                         \
                lds + (db) + WOFF + (h) * 16384 + dsto[1]);                   \
  } while (0)

  short8 aF[8][2];
  short8 bF[4][2];
#define RD_A(dbi, mf)                                                         \
  do {                                                                        \
    aF[mf][0] = *(const short8*)(lds + aB0[dbi] + (mf) * 2048);               \
    aF[mf][1] = *(const short8*)(lds + aB1[dbi] + (mf) * 2048);               \
  } while (0)
#define RD_B(dbi, j)                                                          \
  do {                                                                        \
    bF[j][0] = *(const short8*)(lds + bB0[dbi] + (j) * 8192);                 \
    bF[j][1] = *(const short8*)(lds + bB1[dbi] + (j) * 8192);                 \
  } while (0)
// quadrant (mh, jh): mf 4mh..4mh+3, j 2jh..2jh+1, k 0..1 -> 16 MFMA
#define MFQ(mh, jh)                                                           \
  do {                                                                        \
    __builtin_amdgcn_s_setprio(1);                                            \
    _Pragma("unroll")                                                         \
    for (int k_ = 0; k_ < 2; ++k_)                                            \
      _Pragma("unroll")                                                       \
      for (int mf_ = 4 * (mh); mf_ < 4 * (mh) + 4; ++mf_)                     \
        _Pragma("unroll")                                                     \
        for (int j_ = 2 * (jh); j_ < 2 * (jh) + 2; ++j_)                      \
          acc[mf_][j_] = __builtin_amdgcn_mfma_f32_16x16x32_bf16(             \
              aF[mf_][k_], bF[j_][k_], acc[mf_][j_], 0, 0, 0);                \
    __builtin_amdgcn_s_setprio(0);                                            \
  } while (0)
#define BAR   __builtin_amdgcn_s_barrier()
#define LGKM0                                                                 \
  do {                                                                        \
    asm volatile("s_waitcnt lgkmcnt(0)" ::: "memory");                        \
    __builtin_amdgcn_sched_barrier(0);                                        \
  } while (0)
#define VMC6  asm volatile("s_waitcnt vmcnt(6)" ::: "memory")

  // ---- prologue (r4-identical) ----
  STAGE_W(0, 0, 0); STAGE_A(0, 0, 0); STAGE_A(0, 0, 1); STAGE_W(0, 0, 1);
  STAGE_W(DBUF, 128, 0); STAGE_A(DBUF, 128, 0); STAGE_A(DBUF, 128, 1);
  VMC6;
  BAR;

#pragma unroll 1
  for (int it = 0; it < NI; ++it) {
    const int kt1b  = (2 * it + 1) * 128;
    const int ktn0b = ((2 * it + 2) & 31) * 128;
    const int ktn1b = ((2 * it + 3) & 31) * 128;
    // P1: aF0-3 + bF0-1 (12 reads); stage d1.W1@2i+1
    RD_A(0, 0); RD_A(0, 1); RD_A(0, 2); RD_A(0, 3);
    RD_B(0, 0); RD_B(0, 1);
    STAGE_W(DBUF, kt1b, 1);
    BAR; LGKM0; MFQ(0, 0); BAR;
    // P2: aF4-7 (8 reads); stage d0.W0@2i+2
    RD_A(0, 4); RD_A(0, 5); RD_A(0, 6); RD_A(0, 7);
    STAGE_W(0, ktn0b, 0);
    BAR; LGKM0; MFQ(1, 0); BAR;
    // P3: bF2-3 (4 reads); stage d0.A0
    RD_B(0, 2); RD_B(0, 3);
    STAGE_A(0, ktn0b, 0);
    BAR; LGKM0; MFQ(0, 1); BAR;
    // P4: no reads; stage d0.A1; vmcnt(6) => d1 fully landed
    STAGE_A(0, ktn0b, 1);
    BAR; LGKM0; MFQ(1, 1);
    VMC6; BAR;
    // P5-P8: mirror on dbuf1
    RD_A(1, 0); RD_A(1, 1); RD_A(1, 2); RD_A(1, 3);
    RD_B(1, 0); RD_B(1, 1);
    STAGE_W(0, ktn0b, 1);
    BAR; LGKM0; MFQ(0, 0); BAR;
    RD_A(1, 4); RD_A(1, 5); RD_A(1, 6); RD_A(1, 7);
    STAGE_W(DBUF, ktn1b, 0);
    BAR; LGKM0; MFQ(1, 0); BAR;
    RD_B(1, 2); RD_B(1, 3);
    STAGE_A(DBUF, ktn1b, 0);
    BAR; LGKM0; MFQ(0, 1); BAR;
    STAGE_A(DBUF, ktn1b, 1);
    BAR; LGKM0; MFQ(1, 1);
    VMC6; BAR;
  }

  // ---- epilogue: acc[mf][g]; all 4 gates in same lane/reg ----
  const int colq = ln & 15;
  const int rq   = ln >> 4;
  float* outh = out;
  float* outC = out + (size_t)B_SZ * H_SZ;
  const int n = n0g + wn * 16 + colq;
  const float vbf = bf_[n], vbi = bi_[n], vbo = bo_[n], vbc = bc_[n];
#pragma unroll
  for (int mf = 0; mf < 8; ++mf) {
#pragma unroll
    for (int r = 0; r < 4; ++r) {
      int row = b0 + wm * 128 + mf * 16 + rq * 4 + r;
      float fg = sigmoidf_(acc[mf][0][r] + vbf);
      float ig = sigmoidf_(acc[mf][1][r] + vbi);
      float og = sigmoidf_(acc[mf][2][r] + vbo);
      float cg = tanhf_  (acc[mf][3][r] + vbc);
      float cp = Cp[(size_t)row * H_SZ + n];
      float Ct = fg * cp + ig * cg;
      float ht = og * tanhf_(Ct);
      outh[(size_t)row * H_SZ + n] = ht;
      outC[(size_t)row * H_SZ + n] = Ct;
    }
  }
#undef STAGE_A
#undef STAGE_W
#undef RD_A
#undef RD_B
#undef MFQ
#undef BAR
#undef LGKM0
#undef VMC6
}

extern "C" void kernel_launch(void* const* d_in, const int* in_sizes, int n_in,
                              void* d_out, int out_size, void* d_ws, size_t ws_size,
                              hipStream_t stream) {
  const float* x  = (const float*)d_in[0];
  const float* hp = (const float*)d_in[1];
  const float* Cp = (const float*)d_in[2];
  const float* Wf = (const float*)d_in[3];
  const float* bf = (const float*)d_in[4];
  const float* Wi = (const float*)d_in[5];
  const float* bi = (const float*)d_in[6];
  const float* Wc = (const float*)d_in[7];
  const float* bc = (const float*)d_in[8];
  const float* Wo = (const float*)d_in[9];
  const float* bo = (const float*)d_in[10];

  ushort* Wt  = (ushort*)d_ws;                           // 16 MiB
  ushort* Abf = (ushort*)((char*)d_ws + (16u << 20));    // 32 MiB

  dim3 gridT(16, 32, 4);
  convert_w_kernel<<<gridT, 256, 0, stream>>>(Wf, Wi, Wo, Wc, Wt);
  convert_a_kernel<<<8192, 256, 0, stream>>>(x, hp, Abf);

  lstm_fused_kernel<<<512, 512, 0, stream>>>(Cp, Wt, Abf,
                                             bf, bi, bo, bc, (float*)d_out);
}